// Round 10
// baseline (367.450 us; speedup 1.0000x reference)
//
#include <hip/hip_runtime.h>

// int4 weight-only quantized GEMV: out[n] = sum_k A[k] * W[n,k]
//   W[n,k] = (nib(B)[n,k] - 8) * scale[n, k/32] + zero[n, k/32]
// M=1, K=8192, N=16384, GROUP=32.
//
// R17 = R14 resubmit (never ran: container infra failure), re-audited.
// Consolidated model: 7 structures x 2 mappings x 2 datapaths all ~100 us
// cold; R15 counters show warm serviced rate ~6 TB/s while the HBM-sourced
// component pins at 3.2-3.4 TB/s (= ~425 GB/s/XCD, smells like per-XCD L2
// line-fill port); fills (no read-allocate) write 6.7 TB/s. Only mechanism
// matching all data: cold reads are capped by L2 ALLOCATE bandwidth.
// Fix under test: B loads as global_load_dwordx4 sc0 sc1 nt (system-scope
// non-temporal = no L1/L2 allocate, stream from fabric). Loop is barrier-
// free (red2 slots are per-wave private), all loop vmem is asm volatile ->
// exact monotone vmcnt: 8 ops/tile, WAITV(8) one tile ahead, sched_barrier
// after each wait (rule #18). Compiler-tracked A-loads finish in prologue;
// its conservative waitcnts can only over-wait, never under-wait.

#define TPB   512
#define ROWS  2
#define TILES 16
#define CROWS (ROWS * TILES)   // 32 rows per block; grid 512 = 2 blocks/CU

typedef int   ivec4 __attribute__((ext_vector_type(4)));
typedef float fvec2 __attribute__((ext_vector_type(2)));

// B: system-scope non-temporal (no L2 allocate). SZ: normal cached.
#define NT16(dst, p) asm volatile("global_load_dwordx4 %0, %1, off sc0 sc1 nt" \
                                  : "=v"(dst) : "v"(p) : "memory")
#define LD8(dst, p)  asm volatile("global_load_dwordx2 %0, %1, off"            \
                                  : "=v"(dst) : "v"(p) : "memory")
#define WAITV(n)     do { asm volatile("s_waitcnt vmcnt(" n ")" ::: "memory"); \
                          __builtin_amdgcn_sched_barrier(0); } while (0)

__global__ __launch_bounds__(TPB, 4) void gemv_w4str(
    const float4* __restrict__ A4,   // 8192 f32 = 2048 float4
    const ivec4*  __restrict__ B,    // [N, 1024] (16B = 4 int32 = 8 k)
    const fvec2*  __restrict__ SZ,   // [N, 256] (scale, zero) f32 pairs
    float* __restrict__ out,         // [N] f32
    int N)
{
    const int t    = threadIdx.x;
    const int lane = t & 63;
    const int w    = t >> 6;
    const int row0 = blockIdx.x * CROWS;
    const int g0   = t >> 2;          // quant group of ivec4 index t

    __shared__ float red2[CROWS][8];  // per-row per-wave partials, 1 KB

    // ---- A -> regs once (thread t covers ivec4 t and t+512 of every row) ---
    float a[2][8];
    float sAv[2];
#pragma unroll
    for (int j = 0; j < 2; ++j) {
        const int i = t + 512 * j;
        const float4 x = A4[2 * i];
        const float4 y = A4[2 * i + 1];
        a[j][0] = x.x; a[j][1] = x.y; a[j][2] = x.z; a[j][3] = x.w;
        a[j][4] = y.x; a[j][5] = y.y; a[j][6] = y.z; a[j][7] = y.w;
        sAv[j] = ((x.x + x.y) + (x.z + x.w)) + ((y.x + y.y) + (y.z + y.w));
    }

    ivec4 bA[4], bB[4];               // [r*2+j] : r in {0,1}, j in {0,1}
    fvec2 szA[4], szB[4];

    // issue tile T: exactly 8 asm vmem ops (4x B16 + 4x SZ8), volatile-ordered
    auto issue = [&](int T, ivec4 (&b)[4], fvec2 (&sz)[4]) {
        const int rt = row0 + T * ROWS;
        const ivec4* Bp = B + (size_t)rt * 1024 + t;
        NT16(b[0], Bp);                // r0 j0 (row rt,   ivec4 t)
        NT16(b[1], Bp + 512);          // r0 j1 (row rt,   ivec4 t+512)
        NT16(b[2], Bp + 1024);         // r1 j0 (row rt+1, ivec4 t)
        NT16(b[3], Bp + 1536);         // r1 j1
        const fvec2* Sp = SZ + (size_t)rt * 256 + g0;
        LD8(sz[0], Sp);                // r0 j0 (group g0)
        LD8(sz[1], Sp + 128);          // r0 j1 (group g0+128)
        LD8(sz[2], Sp + 256);          // r1 j0
        LD8(sz[3], Sp + 384);          // r1 j1
    };

    // consume tile whose regs are ready; park row partials in red2[rr+r][w]
    auto consume = [&](const ivec4 (&b)[4], const fvec2 (&sz)[4], int rr) {
        float acc[ROWS];
#pragma unroll
        for (int r = 0; r < ROWS; ++r) acc[r] = 0.0f;
#pragma unroll
        for (int r = 0; r < ROWS; ++r) {
#pragma unroll
            for (int j = 0; j < 2; ++j) {
                const ivec4 bb = b[r * 2 + j];
                const fvec2 ss = sz[r * 2 + j];
                const int c0 = bb[0], c1 = bb[1], c2 = bb[2], c3 = bb[3];
                float dot = 0.0f;
                dot = fmaf(a[j][0], (float)(c0 & 0xF),        dot);
                dot = fmaf(a[j][1], (float)((c0 >> 4) & 0xF), dot);
                dot = fmaf(a[j][2], (float)(c1 & 0xF),        dot);
                dot = fmaf(a[j][3], (float)((c1 >> 4) & 0xF), dot);
                dot = fmaf(a[j][4], (float)(c2 & 0xF),        dot);
                dot = fmaf(a[j][5], (float)((c2 >> 4) & 0xF), dot);
                dot = fmaf(a[j][6], (float)(c3 & 0xF),        dot);
                dot = fmaf(a[j][7], (float)((c3 >> 4) & 0xF), dot);
                acc[r] = fmaf(ss[0], dot, acc[r]);
                acc[r] = fmaf(fmaf(-8.0f, ss[0], ss[1]), sAv[j], acc[r]);
            }
        }
#pragma unroll
        for (int r = 0; r < ROWS; ++r) {
            float v = acc[r];
#pragma unroll
            for (int off = 32; off > 0; off >>= 1)
                v += __shfl_down(v, off, 64);
            if (lane == 0) red2[rr + r][w] = v;
        }
    };

    // ---- prologue: two tiles in flight ----
    issue(0, bA, szA);
    issue(1, bB, szB);

    // ---- barrier-free pipelined loop: 2 tiles / iteration ----
    for (int TT = 0; TT < TILES; TT += 2) {
        // tile TT (set A): tile TT+1's 8 ops may stay in flight
        WAITV("8");
        consume(bA, szA, TT * ROWS);
        if (TT + 2 < TILES) issue(TT + 2, bA, szA);

        // tile TT+1 (set B): newer ops = tile TT+2's 8, if issued
        if (TT + 2 < TILES) WAITV("8"); else WAITV("0");
        consume(bB, szB, (TT + 1) * ROWS);
        if (TT + 3 < TILES) issue(TT + 3, bB, szB);
    }

    // ---- epilogue: one barrier, one coalesced store pass ----
    __syncthreads();
    if (t < CROWS) {
        const int n = row0 + t;
        if (n < N) {
            float v = 0.0f;
#pragma unroll
            for (int w2 = 0; w2 < 8; ++w2) v += red2[t][w2];
            out[n] = v;
        }
    }
}

extern "C" void kernel_launch(void* const* d_in, const int* in_sizes, int n_in,
                              void* d_out, int out_size, void* d_ws, size_t ws_size,
                              hipStream_t stream) {
    const float4* A4 = (const float4*)d_in[0];   // f32[8192]
    const ivec4*  B  = (const ivec4*)d_in[1];    // int32[N, 4096]
    const fvec2*  SZ = (const fvec2*)d_in[2];    // f32[N, 256, 2]
    float* out = (float*)d_out;                  // f32[N]

    const int N = out_size;                      // 16384
    gemv_w4str<<<N / CROWS, TPB, 0, stream>>>(A4, B, SZ, out, N);
}

// Round 11
// 350.034 us; speedup vs baseline: 1.0498x; 1.0498x over previous
//
#include <hip/hip_runtime.h>

// int4 weight-only quantized GEMV: out[n] = sum_k A[k] * W[n,k]
//   W[n,k] = (nib(B)[n,k] - 8) * scale[n, k/32] + zero[n, k/32]
// M=1, K=8192, N=16384, GROUP=32.
//
// R18 = REVERT TO SESSION BEST (R16, 350.8 us). Final model, built from
// R15's direct counters: MI355X cold-READ path caps at ~3.3-3.4 TB/s
// (loads-only probe: 3.4 TB/s HBM, 0.1% VALU, 224 KB/CU outstanding;
// warm serviced rate ~6 TB/s -> CU return machinery fine, HBM read pinned).
// All known-good "6+ TB/s" numbers are mixed read+write (m13 copy = 3.15
// read + 3.15 write; fills = 6.7 pure-write). Roofline: 302 MB irreducible
// cold traffic / 3.35 TB/s = ~90 us; gemv measures ~97-100 us (~8% over,
// epilogue+launch). Exhausted: 7 issue structures, 2 address mappings,
// 2 datapaths (VGPR / gload_lds-DMA), 2 cache policies (allocate / sc0sc1nt),
// occupancy 16 & 32 waves/CU, barrier-free counted-vmcnt pipeline. All ~equal;
// cache-bypass and DMA regress. This is the memory-bound limit.

#define TPB   512
#define ROWS  2
#define TILES 16
#define CROWS (ROWS * TILES)   // 32 rows per block

typedef int   ivec4 __attribute__((ext_vector_type(4)));
typedef float fvec2 __attribute__((ext_vector_type(2)));

__global__ __launch_bounds__(TPB, 4) void gemv_w4il(
    const float4* __restrict__ A4,   // 8192 f32 = 2048 float4
    const ivec4*  __restrict__ B,    // [N, 1024] (16B = 4 int32 = 8 k)
    const fvec2*  __restrict__ SZ,   // [N, 256] (scale, zero) f32 pairs
    float* __restrict__ out,         // [N] f32
    int N)
{
    const int t      = threadIdx.x;
    const int b      = blockIdx.x;
    const int stride = gridDim.x;     // 512: row for slot s is b + s*stride
    const int g0     = t >> 2;

    __shared__ fvec2 sz_s[2][ROWS * 256];
    __shared__ float red[2][ROWS][TPB / 64];

    // ---- A -> regs once (thread t covers ivec4 t and t+512 of every row) ---
    float a[2][8];
    float sA[2];
#pragma unroll
    for (int j = 0; j < 2; ++j) {
        const int i = t + 512 * j;
        const float4 x = A4[2 * i];
        const float4 y = A4[2 * i + 1];
        a[j][0] = x.x; a[j][1] = x.y; a[j][2] = x.z; a[j][3] = x.w;
        a[j][4] = y.x; a[j][5] = y.y; a[j][6] = y.z; a[j][7] = y.w;
        sA[j] = ((x.x + x.y) + (x.z + x.w)) + ((y.x + y.y) + (y.z + y.w));
    }

    ivec4 bufA[ROWS][2], bufB[ROWS][2];
    fvec2 szrA, szrB;

    // tile T covers rows n_r = b + (T*ROWS + r)*stride, r = 0..1
    auto issue = [&](int T, ivec4 (&buf)[ROWS][2], fvec2& szr) {
        const int rr = t >> 8;                    // 0 or 1
        const int gg = t & 255;
        const int ns = b + (T * ROWS + rr) * stride;
        szr = __builtin_nontemporal_load(&SZ[(size_t)ns * 256 + gg]);
#pragma unroll
        for (int r = 0; r < ROWS; ++r) {
            const int n = b + (T * ROWS + r) * stride;
            const ivec4* Bp = B + (size_t)n * 1024 + t;
#pragma unroll
            for (int j = 0; j < 2; ++j)
                buf[r][j] = __builtin_nontemporal_load(&Bp[512 * j]);
        }
    };

    auto consume = [&](const ivec4 (&buf)[ROWS][2], const fvec2* szl,
                       float (&redb)[ROWS][TPB / 64]) {
        float acc[ROWS];
#pragma unroll
        for (int r = 0; r < ROWS; ++r) acc[r] = 0.0f;
#pragma unroll
        for (int r = 0; r < ROWS; ++r) {
#pragma unroll
            for (int j = 0; j < 2; ++j) {
                const fvec2 sz = szl[r * 256 + g0 + 128 * j];
                const int b0 = buf[r][j][0], b1 = buf[r][j][1];
                const int b2 = buf[r][j][2], b3 = buf[r][j][3];
                float dot = 0.0f;
                dot = fmaf(a[j][0], (float)(b0 & 0xF),        dot);
                dot = fmaf(a[j][1], (float)((b0 >> 4) & 0xF), dot);
                dot = fmaf(a[j][2], (float)(b1 & 0xF),        dot);
                dot = fmaf(a[j][3], (float)((b1 >> 4) & 0xF), dot);
                dot = fmaf(a[j][4], (float)(b2 & 0xF),        dot);
                dot = fmaf(a[j][5], (float)((b2 >> 4) & 0xF), dot);
                dot = fmaf(a[j][6], (float)(b3 & 0xF),        dot);
                dot = fmaf(a[j][7], (float)((b3 >> 4) & 0xF), dot);
                acc[r] = fmaf(sz[0], dot, acc[r]);
                acc[r] = fmaf(fmaf(-8.0f, sz[0], sz[1]), sA[j], acc[r]);
            }
        }
        const int lane = t & 63;
        const int w    = t >> 6;
#pragma unroll
        for (int r = 0; r < ROWS; ++r) {
            float v = acc[r];
#pragma unroll
            for (int off = 32; off > 0; off >>= 1)
                v += __shfl_down(v, off, 64);
            if (lane == 0) redb[r][w] = v;
        }
    };

    auto store2 = [&](int T, const float (&redb)[ROWS][TPB / 64]) {
        if (t < ROWS) {
            const int n = b + (T * ROWS + t) * stride;
            if (n < N) {
                float v = 0.0f;
#pragma unroll
                for (int w2 = 0; w2 < TPB / 64; ++w2) v += redb[t][w2];
                out[n] = v;
            }
        }
    };

    issue(0, bufA, szrA);
    sz_s[0][t] = szrA;
    __syncthreads();

    for (int TT = 0; TT < TILES; TT += 2) {
        if (TT + 1 < TILES) issue(TT + 1, bufB, szrB);
        consume(bufA, &sz_s[0][0], red[0]);
        if (TT + 1 < TILES) sz_s[1][t] = szrB;
        __syncthreads();
        store2(TT, red[0]);

        if (TT + 2 < TILES) issue(TT + 2, bufA, szrA);
        consume(bufB, &sz_s[1][0], red[1]);
        if (TT + 2 < TILES) sz_s[0][t] = szrA;
        __syncthreads();
        store2(TT + 1, red[1]);
    }
}

extern "C" void kernel_launch(void* const* d_in, const int* in_sizes, int n_in,
                              void* d_out, int out_size, void* d_ws, size_t ws_size,
                              hipStream_t stream) {
    const float4* A4 = (const float4*)d_in[0];   // f32[8192]
    const ivec4*  B  = (const ivec4*)d_in[1];    // int32[N, 4096]
    const fvec2*  SZ = (const fvec2*)d_in[2];    // f32[N, 256, 2]
    float* out = (float*)d_out;                  // f32[N]

    const int N = out_size;                      // 16384
    gemv_w4il<<<N / CROWS, TPB, 0, stream>>>(A4, B, SZ, out, N);
}